// Round 4
// baseline (173.450 us; speedup 1.0000x reference)
//
#include <hip/hip_runtime.h>
#include <hip/hip_bf16.h>

#define NE 32
#define MM 1024
#define KK 512
#define NN 512
#define BM 64    // rows per tile
#define BN 128   // cols per tile -> 4 n-tiles
#define BK 32    // fp32 elems per LDS row = 128 B = 8 x 16B units, XOR-swizzled

typedef __attribute__((ext_vector_type(8))) short bf16x8;
typedef __attribute__((ext_vector_type(4))) float floatx4;

__device__ __forceinline__ short f2bf(float f) {
  union { __hip_bfloat16 b; short s; } u;
  u.b = __float2bfloat16(f);   // RNE
  return u.s;
}

// Fire-and-forget global->LDS DMA (16 B/lane). Linear LDS dest (HW: uniform
// base + lane*16); the bank-conflict swizzle is applied on the SOURCE address
// (per-lane) and mirrored on the ds_read side (both-sides-or-neither rule).
#define GLDS(g, l) __builtin_amdgcn_global_load_lds(                      \
    (const __attribute__((address_space(1))) void*)(g),                   \
    (__attribute__((address_space(3))) void*)(l), 16, 0, 0)

// XCD-partitioned decode: xcd = blockIdx.x & 7, slot = blockIdx.x >> 3.
// XCD x owns experts {x, x+8, x+16, x+24}; per expert (expert-major):
//   [4*vt GEMM tiles (mt-major, nt fastest)] ++ [(16-vt) zero 64x512 stripes]
extern "C" __global__ __launch_bounds__(256, 3)
void expert_gemm(const float* __restrict__ A, const float* __restrict__ B,
                 const int* __restrict__ cnts, float* __restrict__ C)
{
  const int b    = blockIdx.x;
  const int tid  = threadIdx.x;
  const int xcd  = b & 7;
  const int slot = b >> 3;

  int e = -1, mt = 0, nt = 0, zfill = 0;
  int base = 0;
#pragma unroll
  for (int i = 0; i < 4; ++i) {
    int ei = xcd + (i << 3);
    int vt = (cnts[ei] + 63) >> 6;
    int tot = 16 + 3 * vt;
    if (e < 0 && slot < base + tot) {
      int r = slot - base;
      int g = vt << 2;
      e = ei;
      if (r < g) { mt = r >> 2; nt = r & 3; }
      else       { zfill = 1; mt = vt + (r - g); }
    }
    base += tot;
  }
  if (e < 0) return;

  if (zfill) {
    // zero-fill a 64x512 stripe (harness poisons d_out each launch)
    float* Ce = C + ((size_t)e * MM + mt * BM) * NN;
    float4 zf = make_float4(0.f, 0.f, 0.f, 0.f);
#pragma unroll
    for (int i = 0; i < 32; ++i) {
      int fidx = i * 256 + tid;
      int r = fidx >> 7, c = (fidx & 127) << 2;
      *(float4*)(Ce + (size_t)r * NN + c) = zf;
    }
    return;
  }

  // ---- GEMM tile: C[e][m0:m0+64][n0:n0+128] = A[e] @ B[e]^T ----
  const int m0 = mt * BM, n0 = nt * BN;
  const int cnt = cnts[e];
  const float* Ae = A + ((size_t)e * MM + m0) * KK;
  const float* Be = B + ((size_t)e * NN + n0) * KK;
  float* Ce = C + ((size_t)e * MM + m0) * NN + n0;

  // fp32 staging, double-buffered. Row = 32 floats = 128 B = 8 units of 16 B.
  // Logical unit u of row r lives at phys unit u ^ (r&7) (Latin-square swizzle
  // -> ds_read_b128 frag reads are ~conflict-free).
  __shared__ __align__(16) float sA[2][BM * BK];  // 2 x 8 KB
  __shared__ __align__(16) float sB[2][BN * BK];  // 2 x 16 KB

  const int wave = tid >> 6, lane = tid & 63;
  const int wm = (wave >> 1) * 32, wn = (wave & 1) * 64;  // wave tile: 32x64
  const int fr = lane & 15, kh = lane >> 4;
  const int frs = fr & 7;              // row-swizzle key for frag reads

  // DMA source geometry: each issue covers 8 rows x 128 B = 1 KB = one wave.
  // lane -> row (lane>>3) within the 8-row group, source unit (lane&7)^(lane>>3)
  // so that linear LDS phys unit (lane&7) holds logical unit ((lane&7)^(r&7)).
  const int lr = lane >> 3;
  const int lu = (lane & 7) ^ lr;
  const size_t rowb = (size_t)lr * (KK * 4) + (size_t)lu * 16;  // bytes
  const char* gA = (const char*)Ae;
  const char* gB = (const char*)Be;

  // Per iteration: 24 issues (A:8, B:16) split 6 per wave.
#define STAGE(bufi, KT) do {                                               \
    _Pragma("unroll")                                                      \
    for (int q = 0; q < 2; ++q) {                                          \
      int ia = wave + (q << 2);                                            \
      GLDS(gA + (size_t)(8 * ia) * (KK * 4) + rowb + (size_t)(KT) * 4,     \
           &sA[bufi][ia << 8]);                                            \
    }                                                                      \
    _Pragma("unroll")                                                      \
    for (int q = 0; q < 4; ++q) {                                          \
      int ib = wave + (q << 2);                                            \
      GLDS(gB + (size_t)(8 * ib) * (KK * 4) + rowb + (size_t)(KT) * 4,     \
           &sB[bufi][ib << 8]);                                            \
    }                                                                      \
  } while (0)

  floatx4 acc4[2][4] = {};

  STAGE(0, 0);
  __syncthreads();   // compiler drains vmcnt before s_barrier -> buf0 ready

  int cur = 0;
#pragma unroll
  for (int kt = 0; kt < KK; kt += BK) {
    if (kt + BK < KK) STAGE(cur ^ 1, kt + BK);   // DMA in flight across compute

    const char* bufA = (const char*)sA[cur];
    const char* bufB = (const char*)sB[cur];

    bf16x8 af[2], bfv[4];
#pragma unroll
    for (int i = 0; i < 2; ++i) {
      int rA = wm + (i << 4) + fr;                 // rA&7 == frs
      const char* rb = bufA + rA * 128;
      float4 f0 = *(const float4*)(rb + ((((kh << 1)    ) ^ frs) << 4));
      float4 f1 = *(const float4*)(rb + ((((kh << 1) | 1) ^ frs) << 4));
      af[i] = (bf16x8){ f2bf(f0.x), f2bf(f0.y), f2bf(f0.z), f2bf(f0.w),
                        f2bf(f1.x), f2bf(f1.y), f2bf(f1.z), f2bf(f1.w) };
    }
#pragma unroll
    for (int j = 0; j < 4; ++j) {
      int rB = wn + (j << 4) + fr;                 // rB&7 == frs
      const char* rb = bufB + rB * 128;
      float4 f0 = *(const float4*)(rb + ((((kh << 1)    ) ^ frs) << 4));
      float4 f1 = *(const float4*)(rb + ((((kh << 1) | 1) ^ frs) << 4));
      bfv[j] = (bf16x8){ f2bf(f0.x), f2bf(f0.y), f2bf(f0.z), f2bf(f0.w),
                         f2bf(f1.x), f2bf(f1.y), f2bf(f1.z), f2bf(f1.w) };
    }
#pragma unroll
    for (int i = 0; i < 2; ++i)
#pragma unroll
      for (int j = 0; j < 4; ++j)
        acc4[i][j] = __builtin_amdgcn_mfma_f32_16x16x32_bf16(af[i], bfv[j], acc4[i][j], 0, 0, 0);

    __syncthreads();   // all reads of buf[cur] done AND next-slab DMA landed
    cur ^= 1;
  }
#undef STAGE

  // epilogue: C/D layout col=lane&15, row=(lane>>4)*4+reg (m89/m91-verified)
  const int rbase = (lane >> 4) * 4;
#pragma unroll
  for (int i = 0; i < 2; ++i) {
#pragma unroll
    for (int r = 0; r < 4; ++r) {
      int row = wm + i * 16 + rbase + r;
      bool valid = (m0 + row) < cnt;
#pragma unroll
      for (int j = 0; j < 4; ++j) {
        int col = wn + j * 16 + fr;
        Ce[(size_t)row * NN + col] = valid ? acc4[i][j][r] : 0.0f;
      }
    }
  }
}

extern "C" void kernel_launch(void* const* d_in, const int* in_sizes, int n_in,
                              void* d_out, int out_size, void* d_ws, size_t ws_size,
                              hipStream_t stream) {
  const float* A    = (const float*)d_in[0];
  const float* B    = (const float*)d_in[1];
  const int*   cnts = (const int*)d_in[2];
  float*       C    = (float*)d_out;

  // 8 XCDs x 256 slots; blockIdx & 7 selects XCD (round-robin dispatch)
  hipLaunchKernelGGL(expert_gemm, dim3(2048), dim3(256), 0, stream, A, B, cnts, C);
}

// Round 5
// 164.584 us; speedup vs baseline: 1.0539x; 1.0539x over previous
//
#include <hip/hip_runtime.h>
#include <hip/hip_bf16.h>

#define NE 32
#define MM 1024
#define KK 512
#define NN 512
#define BM 64    // rows per tile
#define BN 128   // cols per tile -> 4 n-tiles
#define BK 32    // fp32 elems per LDS row = 128 B = 8 x 16B units, XOR-swizzled

typedef __attribute__((ext_vector_type(8))) short bf16x8;
typedef __attribute__((ext_vector_type(4))) float floatx4;

__device__ __forceinline__ short f2bf(float f) {
  union { __hip_bfloat16 b; short s; } u;
  u.b = __float2bfloat16(f);   // RNE
  return u.s;
}

// Fire-and-forget global->LDS DMA (16 B/lane). Linear LDS dest (HW: uniform
// base + lane*16); bank-conflict swizzle applied on the SOURCE address and
// mirrored on the ds_read side (both-sides-or-neither, verified round 4).
#define GLDS(g, l) __builtin_amdgcn_global_load_lds(                      \
    (const __attribute__((address_space(1))) void*)(g),                   \
    (__attribute__((address_space(3))) void*)(l), 16, 0, 0)

// XCD-partitioned decode: xcd = blockIdx.x & 7, slot = blockIdx.x >> 3.
// XCD x owns experts {x, x+8, x+16, x+24}; per expert (expert-major):
//   [4*vt GEMM tiles (mt-major, nt fastest)] ++ [(16-vt) zero 64x512 stripes]
extern "C" __global__ __launch_bounds__(256, 3)
void expert_gemm(const float* __restrict__ A, const float* __restrict__ B,
                 const int* __restrict__ cnts, float* __restrict__ C)
{
  const int b    = blockIdx.x;
  const int tid  = threadIdx.x;
  const int xcd  = b & 7;
  const int slot = b >> 3;

  int e = -1, mt = 0, nt = 0, zfill = 0;
  int base = 0;
#pragma unroll
  for (int i = 0; i < 4; ++i) {
    int ei = xcd + (i << 3);
    int vt = (cnts[ei] + 63) >> 6;
    int tot = 16 + 3 * vt;
    if (e < 0 && slot < base + tot) {
      int r = slot - base;
      int g = vt << 2;
      e = ei;
      if (r < g) { mt = r >> 2; nt = r & 3; }
      else       { zfill = 1; mt = vt + (r - g); }
    }
    base += tot;
  }
  if (e < 0) return;

  if (zfill) {
    // zero-fill a 64x512 stripe (harness poisons d_out each launch)
    float* Ce = C + ((size_t)e * MM + mt * BM) * NN;
    float4 zf = make_float4(0.f, 0.f, 0.f, 0.f);
#pragma unroll
    for (int i = 0; i < 32; ++i) {
      int fidx = i * 256 + tid;
      int r = fidx >> 7, c = (fidx & 127) << 2;
      *(float4*)(Ce + (size_t)r * NN + c) = zf;
    }
    return;
  }

  // ---- GEMM tile: C[e][m0:m0+64][n0:n0+128] = A[e] @ B[e]^T ----
  const int m0 = mt * BM, n0 = nt * BN;
  const int cnt = cnts[e];
  const float* Ae = A + ((size_t)e * MM + m0) * KK;
  const float* Be = B + ((size_t)e * NN + n0) * KK;
  float* Ce = C + ((size_t)e * MM + m0) * NN + n0;

  // fp32 staging, double-buffered. Row = 32 floats = 128 B = 8 units of 16 B.
  // Logical unit u of row r lives at phys unit u ^ (r&7).
  __shared__ __align__(16) float sA[2][BM * BK];  // 2 x 8 KB
  __shared__ __align__(16) float sB[2][BN * BK];  // 2 x 16 KB

  const int wave = tid >> 6, lane = tid & 63;
  const int wm = (wave >> 1) * 32, wn = (wave & 1) * 64;  // wave tile: 32x64
  const int fr = lane & 15, kh = lane >> 4;
  const int frs = fr & 7;              // row-swizzle key for frag reads

  // DMA source geometry: each issue covers 8 rows x 128 B = 1 KB per wave.
  const int lr = lane >> 3;
  const int lu = (lane & 7) ^ lr;
  const size_t rowb = (size_t)lr * (KK * 4) + (size_t)lu * 16;  // bytes
  const char* gA = (const char*)Ae;
  const char* gB = (const char*)Be;

  // Per iteration: 24 wave-DMAs (A:8, B:16) split 6 per wave.
#define STAGE(bufi, KT) do {                                               \
    _Pragma("unroll")                                                      \
    for (int q = 0; q < 2; ++q) {                                          \
      int ia = wave + (q << 2);                                            \
      GLDS(gA + (size_t)(8 * ia) * (KK * 4) + rowb + (size_t)(KT) * 4,     \
           &sA[bufi][ia << 8]);                                            \
    }                                                                      \
    _Pragma("unroll")                                                      \
    for (int q = 0; q < 4; ++q) {                                          \
      int ib = wave + (q << 2);                                            \
      GLDS(gB + (size_t)(8 * ib) * (KK * 4) + rowb + (size_t)(KT) * 4,     \
           &sB[bufi][ib << 8]);                                            \
    }                                                                      \
  } while (0)

  floatx4 acc4[2][4] = {};

  STAGE(0, 0);   // 6 DMAs/wave in flight

  int cur = 0;
#pragma unroll
  for (int kt = 0; kt < KK; kt += BK) {
    const bool last = (kt + BK >= KK);

    if (!last) {
      STAGE(cur ^ 1, kt + BK);   // next slab's 6 DMAs join the queue (12 out)
      // counted wait: drain ONLY the previous slab's 6; keep 6 in flight
      asm volatile("s_waitcnt vmcnt(6)" ::: "memory");
    } else {
      asm volatile("s_waitcnt vmcnt(0)" ::: "memory");
    }
    __builtin_amdgcn_s_barrier();        // raw: no compiler vmcnt(0) drain
    __builtin_amdgcn_sched_barrier(0);   // no ds_read hoisted above barrier

    const char* bufA = (const char*)sA[cur];
    const char* bufB = (const char*)sB[cur];

    bf16x8 af[2], bfv[4];
#pragma unroll
    for (int i = 0; i < 2; ++i) {
      int rA = wm + (i << 4) + fr;                 // rA&7 == frs
      const char* rb = bufA + rA * 128;
      float4 f0 = *(const float4*)(rb + ((((kh << 1)    ) ^ frs) << 4));
      float4 f1 = *(const float4*)(rb + ((((kh << 1) | 1) ^ frs) << 4));
      af[i] = (bf16x8){ f2bf(f0.x), f2bf(f0.y), f2bf(f0.z), f2bf(f0.w),
                        f2bf(f1.x), f2bf(f1.y), f2bf(f1.z), f2bf(f1.w) };
    }
#pragma unroll
    for (int j = 0; j < 4; ++j) {
      int rB = wn + (j << 4) + fr;                 // rB&7 == frs
      const char* rb = bufB + rB * 128;
      float4 f0 = *(const float4*)(rb + ((((kh << 1)    ) ^ frs) << 4));
      float4 f1 = *(const float4*)(rb + ((((kh << 1) | 1) ^ frs) << 4));
      bfv[j] = (bf16x8){ f2bf(f0.x), f2bf(f0.y), f2bf(f0.z), f2bf(f0.w),
                         f2bf(f1.x), f2bf(f1.y), f2bf(f1.z), f2bf(f1.w) };
    }
#pragma unroll
    for (int i = 0; i < 2; ++i)
#pragma unroll
      for (int j = 0; j < 4; ++j)
        acc4[i][j] = __builtin_amdgcn_mfma_f32_16x16x32_bf16(af[i], bfv[j], acc4[i][j], 0, 0, 0);

    if (!last) {
      __builtin_amdgcn_sched_barrier(0);  // reads stay above the end barrier
      __builtin_amdgcn_s_barrier();       // all waves done reading buf[cur]
      __builtin_amdgcn_sched_barrier(0);  // next STAGE stays below it
    }
    cur ^= 1;
  }
#undef STAGE

  // epilogue: C/D layout col=lane&15, row=(lane>>4)*4+reg (m89/m91-verified)
  const int rbase = (lane >> 4) * 4;
#pragma unroll
  for (int i = 0; i < 2; ++i) {
#pragma unroll
    for (int r = 0; r < 4; ++r) {
      int row = wm + i * 16 + rbase + r;
      bool valid = (m0 + row) < cnt;
#pragma unroll
      for (int j = 0; j < 4; ++j) {
        int col = wn + j * 16 + fr;
        Ce[(size_t)row * NN + col] = valid ? acc4[i][j][r] : 0.0f;
      }
    }
  }
}

extern "C" void kernel_launch(void* const* d_in, const int* in_sizes, int n_in,
                              void* d_out, int out_size, void* d_ws, size_t ws_size,
                              hipStream_t stream) {
  const float* A    = (const float*)d_in[0];
  const float* B    = (const float*)d_in[1];
  const int*   cnts = (const int*)d_in[2];
  float*       C    = (float*)d_out;

  // 8 XCDs x 256 slots; blockIdx & 7 selects XCD (round-robin dispatch)
  hipLaunchKernelGGL(expert_gemm, dim3(2048), dim3(256), 0, stream, A, B, cnts, C);
}